// Round 4
// baseline (18982.123 us; speedup 1.0000x reference)
//
#include <hip/hip_runtime.h>
#include <math.h>

#define T_LEN 8192
#define NWG 4

typedef _Float16 half2_t __attribute__((ext_vector_type(2)));
union HU { unsigned u; half2_t h2; };

// DPP helpers (ctrl must be literal): butterfly within rows of 16 lanes.
#define DPP_ADD(x, ctrl) ((x) + __int_as_float(__builtin_amdgcn_update_dpp(0, __float_as_int(x), (ctrl), 0xF, 0xF, true)))
#define DPP_MAX(x, ctrl) fmaxf((x), __int_as_float(__builtin_amdgcn_update_dpp(0, __float_as_int(x), (ctrl), 0xF, 0xF, true)))

__device__ __forceinline__ float fsig(float x) {
    x = fminf(30.f, fmaxf(-30.f, x));
    float e = __expf(-x);
    return __builtin_amdgcn_rcpf(1.f + e);
}
__device__ __forceinline__ float ftanh(float x) {
    x = fminf(15.f, fmaxf(-15.f, x));
    float e = __expf(-2.f * x);
    return (1.f - e) * __builtin_amdgcn_rcpf(1.f + e);
}
__device__ __forceinline__ unsigned short f16b(float x) {
    _Float16 h = (_Float16)x;
    return __builtin_bit_cast(unsigned short, h);
}
__device__ __forceinline__ float dot2f(unsigned wa_u, unsigned hb_u, float acc) {
    HU wa; wa.u = wa_u;
    HU hb; hb.u = hb_u;
#if __has_builtin(__builtin_amdgcn_fdot2)
    return __builtin_amdgcn_fdot2(wa.h2, hb.h2, acc, false);
#else
    return acc + (float)wa.h2.x * (float)hb.h2.x + (float)wa.h2.y * (float)hb.h2.y;
#endif
}

// ---------------------------------------------------------------------------
// Kernel 1: pre = relu(embed_W[docs]) @ w_ih^T + (b_ih + b_hh)   (T x 1024)
// ---------------------------------------------------------------------------
__global__ __launch_bounds__(256, 4) void gemm_pre(
    const int* __restrict__ docs,
    const float* __restrict__ embW,
    const float* __restrict__ w_ih,
    const float* __restrict__ b_ih,
    const float* __restrict__ b_hh,
    float* __restrict__ pre)
{
    __shared__ __align__(16) float As[16][68];
    __shared__ __align__(16) float Bs[16][68];
    __shared__ int rowid[64];
    const int bt = blockIdx.x;   // 128 t-tiles
    const int bj = blockIdx.y;   // 16 j-tiles
    const int tid = threadIdx.x;
    if (tid < 64) rowid[tid] = docs[bt * 64 + tid];
    __syncthreads();
    const int ti = tid & 15, tj = tid >> 4;
    const int r = tid & 63;
    const int kk4 = (tid >> 6) * 4;
    float acc[4][4];
#pragma unroll
    for (int ii = 0; ii < 4; ++ii)
#pragma unroll
        for (int jj = 0; jj < 4; ++jj) acc[ii][jj] = 0.f;

    for (int k0 = 0; k0 < 256; k0 += 16) {
        float4 av = *(const float4*)(embW + (size_t)rowid[r] * 256 + k0 + kk4);
        float4 bv = *(const float4*)(w_ih + (size_t)(bj * 64 + r) * 256 + k0 + kk4);
        As[kk4 + 0][r] = fmaxf(av.x, 0.f);
        As[kk4 + 1][r] = fmaxf(av.y, 0.f);
        As[kk4 + 2][r] = fmaxf(av.z, 0.f);
        As[kk4 + 3][r] = fmaxf(av.w, 0.f);
        Bs[kk4 + 0][r] = bv.x;
        Bs[kk4 + 1][r] = bv.y;
        Bs[kk4 + 2][r] = bv.z;
        Bs[kk4 + 3][r] = bv.w;
        __syncthreads();
#pragma unroll
        for (int kk = 0; kk < 16; ++kk) {
            float4 a = *(const float4*)&As[kk][ti * 4];
            float4 b = *(const float4*)&Bs[kk][tj * 4];
            acc[0][0] += a.x * b.x; acc[0][1] += a.x * b.y; acc[0][2] += a.x * b.z; acc[0][3] += a.x * b.w;
            acc[1][0] += a.y * b.x; acc[1][1] += a.y * b.y; acc[1][2] += a.y * b.z; acc[1][3] += a.y * b.w;
            acc[2][0] += a.z * b.x; acc[2][1] += a.z * b.y; acc[2][2] += a.z * b.z; acc[2][3] += a.z * b.w;
            acc[3][0] += a.w * b.x; acc[3][1] += a.w * b.y; acc[3][2] += a.w * b.z; acc[3][3] += a.w * b.w;
        }
        __syncthreads();
    }
#pragma unroll
    for (int ii = 0; ii < 4; ++ii) {
        int t = bt * 64 + ti * 4 + ii;
#pragma unroll
        for (int jj = 0; jj < 4; ++jj) {
            int j = bj * 64 + tj * 4 + jj;
            pre[(size_t)t * 1024 + j] = acc[ii][jj] + b_ih[j] + b_hh[j];
        }
    }
}

// ---------------------------------------------------------------------------
// Kernel 2: sequential LSTM scan. 4 WGs x 512 threads.
// Wave wv of WG w owns hidden units j = w*64 + wv*8 .. +8 (all 4 gates).
// Inter-WG sync: tagged words hbuf[parity][elem] = (f16(h)<<16) | (t+1).
// Release store, relaxed polls (tag+payload atomic in one word) -> ONE LLC
// round trip per step. Spin watchdog: total poll budget per thread; on
// exhaustion proceed (visible absmax failure instead of device hang).
// ---------------------------------------------------------------------------
__global__ __launch_bounds__(512, 2) void lstm_scan(
    const float* __restrict__ pre,   // (T, 1024)
    const float* __restrict__ w_hh,  // (1024, 256)
    float* __restrict__ hs,          // (T, 256) fp32
    unsigned* __restrict__ hbuf)     // [2][256] tagged words, zeroed per launch
{
    const int wgid = blockIdx.x;
    const int tid  = threadIdx.x;
    const int lane = tid & 63;
    const int wv   = tid >> 6;        // wave 0..7
    const int rs   = lane >> 4;       // gate index 0..3 (i,f,g,o)
    const int kq   = lane & 15;       // k-chunk 0..15 (16 h elems each)

    // pack weights to f16 pairs: 8 rows x 8 dwords = 64 VGPRs
    unsigned wpk[64];
#pragma unroll
    for (int rr = 0; rr < 8; ++rr) {
        int grow = rs * 256 + wgid * 64 + wv * 8 + rr;
        const float* src = w_hh + (size_t)grow * 256 + kq * 16;
#pragma unroll
        for (int q = 0; q < 8; ++q) {
            HU u;
            half2_t h2;
            h2.x = (_Float16)src[2 * q];
            h2.y = (_Float16)src[2 * q + 1];
            u.h2 = h2;
            wpk[rr * 8 + q] = u.u;
        }
    }

    const bool has_pre = (kq < 8);
    const int grow_pre = rs * 256 + wgid * 64 + wv * 8 + kq;  // valid if kq<8
    float pre_cur = has_pre ? pre[grow_pre] : 0.f;

    const bool is_upd = (lane < 8);
    const int j_unit = wgid * 64 + wv * 8 + lane;              // valid if lane<8
    float c_reg = 0.f;

    // h as f16, 16 chunks of 16, chunk stride 24 ushorts (48 B, 16B-aligned)
    __shared__ __align__(16) unsigned short sh16[16 * 24];
    for (int i = tid; i < 16 * 24; i += 512) sh16[i] = 0;

    const int e_rd = tid;                                      // reader element
    const bool is_rd = (tid < 256) && ((tid >> 6) != wgid);
    long long spin_budget = 4000000;   // watchdog: ~50x normal total usage
    __syncthreads();

    for (int t = 0; t < T_LEN; ++t) {
        // ---- load my h chunk: 16 f16 = 8 packed dwords ----
        const uint4* hp = (const uint4*)((const char*)sh16 + kq * 48);
        uint4 A = hp[0], B = hp[1];
        unsigned hvv[8];
        hvv[0] = A.x; hvv[1] = A.y; hvv[2] = A.z; hvv[3] = A.w;
        hvv[4] = B.x; hvv[5] = B.y; hvv[6] = B.z; hvv[7] = B.w;
        __syncthreads();   // all waves consumed sh16; safe to overwrite below

        // ---- packed-f16 dots + 16-lane butterfly reduce ----
        float a[8];
#pragma unroll
        for (int rr = 0; rr < 8; ++rr) {
            float s = 0.f;
#pragma unroll
            for (int q = 0; q < 8; ++q) s = dot2f(wpk[rr * 8 + q], hvv[q], s);
            s = DPP_ADD(s, 0xB1);   // quad_perm [1,0,3,2]
            s = DPP_ADD(s, 0x4E);   // quad_perm [2,3,0,1]
            s = DPP_ADD(s, 0x141);  // row_half_mirror
            s = DPP_ADD(s, 0x140);  // row_mirror
            a[rr] = s;
        }
        // select a[kq&7] (static ladder)
        {
            int ks = kq & 7;
            float sel = a[0];
            sel = (ks == 1) ? a[1] : sel;
            sel = (ks == 2) ? a[2] : sel;
            sel = (ks == 3) ? a[3] : sel;
            sel = (ks == 4) ? a[4] : sel;
            sel = (ks == 5) ? a[5] : sel;
            sel = (ks == 6) ? a[6] : sel;
            sel = (ks == 7) ? a[7] : sel;
            if (has_pre) {
                sel += pre_cur;
                int tn = (t + 1 < T_LEN) ? (t + 1) : t;
                pre_cur = pre[(size_t)tn * 1024 + grow_pre];  // prefetch
            }
            // gather 4 gates onto lanes 0..7 (unit u = lane)
            float gi = sel;
            float gf = __shfl(sel, lane + 16, 64);
            float gg = __shfl(sel, lane + 32, 64);
            float go = __shfl(sel, lane + 48, 64);
            if (is_upd) {
                float si = fsig(gi);
                float sf = fsig(gf);
                float tg = ftanh(gg);
                float so = fsig(go);
                c_reg = sf * c_reg + si * tg;
                float h = so * ftanh(c_reg);
                unsigned short hb16 = f16b(h);
                unsigned word = ((unsigned)hb16 << 16) | (unsigned)(t + 1);
                __hip_atomic_store(&hbuf[(t & 1) * 256 + j_unit], word,
                                   __ATOMIC_RELEASE, __HIP_MEMORY_SCOPE_AGENT);
                hs[(size_t)t * 256 + j_unit] = h;
                sh16[(j_unit >> 4) * 24 + (j_unit & 15)] = hb16;
            }
        }

        // ---- poll remote tagged words (192 remote elems) with watchdog ----
        if (is_rd) {
            unsigned tgt = (unsigned)(t + 1);
            unsigned w = __hip_atomic_load(&hbuf[(t & 1) * 256 + e_rd],
                                           __ATOMIC_RELAXED, __HIP_MEMORY_SCOPE_AGENT);
            while ((w & 0xffffu) != tgt && spin_budget > 0) {
                --spin_budget;
                w = __hip_atomic_load(&hbuf[(t & 1) * 256 + e_rd],
                                      __ATOMIC_RELAXED, __HIP_MEMORY_SCOPE_AGENT);
            }
            sh16[(e_rd >> 4) * 24 + (e_rd & 15)] = (unsigned short)(w >> 16);
        }
        __syncthreads();
    }
}

// ---------------------------------------------------------------------------
// Kernel 3: conv (FN=128, FL=5) over hs + per-block max over its 64 t's.
// ---------------------------------------------------------------------------
__global__ __launch_bounds__(256) void conv_pool(
    const float* __restrict__ hs,    // (T, 256)
    const float* __restrict__ cw,    // (128, 1, 5, 256)
    const float* __restrict__ cb,    // (128,)
    float* __restrict__ part)        // (128 blocks, 128 n)
{
    __shared__ __align__(16) float hst[68 * 260];
    __shared__ __align__(16) float cwS[128 * 68];
    const int blk = blockIdx.x;
    const int t0 = blk * 64;
    const int tid = threadIdx.x;
    const int i = tid & 15;    // t-lane
    const int g = tid >> 4;    // n-group 0..15

    for (int e = tid; e < 68 * 64; e += 256) {
        int rr = e >> 6;
        int c4 = (e & 63) * 4;
        int tg = t0 + rr; if (tg > 8191) tg = 8191;
        float4 v = *(const float4*)(hs + (size_t)tg * 256 + c4);
        *(float4*)&hst[rr * 260 + c4] = v;
    }

    float acc[4][8];
#pragma unroll
    for (int tt = 0; tt < 4; ++tt)
#pragma unroll
        for (int j = 0; j < 8; ++j) acc[tt][j] = 0.f;

    for (int l = 0; l < 5; ++l) {
        for (int hc = 0; hc < 4; ++hc) {
            __syncthreads();
            {
                int n = tid >> 1;
                int hb = (tid & 1) * 32;
                const float* src = cw + (size_t)n * 1280 + l * 256 + hc * 64 + hb;
                float* dst = &cwS[n * 68 + hb];
#pragma unroll
                for (int q = 0; q < 8; ++q) {
                    float4 v = *(const float4*)(src + 4 * q);
                    *(float4*)(dst + 4 * q) = v;
                }
            }
            __syncthreads();
#pragma unroll 4
            for (int q = 0; q < 16; ++q) {
                float4 hvv[4];
#pragma unroll
                for (int tt = 0; tt < 4; ++tt)
                    hvv[tt] = *(const float4*)&hst[(i + 16 * tt + l) * 260 + hc * 64 + 4 * q];
#pragma unroll
                for (int j = 0; j < 8; ++j) {
                    float4 wv = *(const float4*)&cwS[(g + 16 * j) * 68 + 4 * q];
#pragma unroll
                    for (int tt = 0; tt < 4; ++tt) {
                        acc[tt][j] += hvv[tt].x * wv.x + hvv[tt].y * wv.y
                                    + hvv[tt].z * wv.z + hvv[tt].w * wv.w;
                    }
                }
            }
        }
    }

    float m[8];
#pragma unroll
    for (int j = 0; j < 8; ++j) {
        int n = g + 16 * j;
        float cbn = cb[n];
        float mm = -INFINITY;
#pragma unroll
        for (int tt = 0; tt < 4; ++tt) {
            int t = t0 + i + 16 * tt;
            float v = acc[tt][j] + cbn;
            if (t < 8188) mm = fmaxf(mm, v);
        }
        mm = DPP_MAX(mm, 0xB1);
        mm = DPP_MAX(mm, 0x4E);
        mm = DPP_MAX(mm, 0x141);
        mm = DPP_MAX(mm, 0x140);
        m[j] = mm;
    }
    if (i == 0) {
#pragma unroll
        for (int j = 0; j < 8; ++j)
            part[(size_t)blk * 128 + g + 16 * j] = m[j];
    }
}

// ---------------------------------------------------------------------------
// Kernel 4: final head — pool-reduce, logits, log_softmax, loss + acc.
// ---------------------------------------------------------------------------
__global__ void final_head(
    const float* __restrict__ part,      // (128, 128)
    const float* __restrict__ logits_w,  // (20, 128)
    const float* __restrict__ logits_b,  // (20,)
    const int* __restrict__ labels,
    float* __restrict__ out)             // [loss, acc]
{
    __shared__ float pooled[128];
    __shared__ float lgt[20];
    int tid = threadIdx.x;  // 128 threads
    float mx = -INFINITY;
    for (int b = 0; b < 128; ++b) mx = fmaxf(mx, part[(size_t)b * 128 + tid]);
    pooled[tid] = mx;
    __syncthreads();
    if (tid < 20) {
        float s = logits_b[tid];
        for (int k = 0; k < 128; ++k) s += logits_w[tid * 128 + k] * pooled[k];
        lgt[tid] = s;
    }
    __syncthreads();
    if (tid == 0) {
        float m = lgt[0]; int am = 0;
        for (int c2 = 1; c2 < 20; ++c2) { if (lgt[c2] > m) { m = lgt[c2]; am = c2; } }
        float se = 0.f;
        for (int c2 = 0; c2 < 20; ++c2) se += expf(lgt[c2] - m);
        float lse = m + logf(se);
        int lbl = labels[0];
        out[0] = -(lgt[lbl] - lse);
        out[1] = (am == lbl) ? 1.f : 0.f;
    }
}

// ---------------------------------------------------------------------------
extern "C" void kernel_launch(void* const* d_in, const int* in_sizes, int n_in,
                              void* d_out, int out_size, void* d_ws, size_t ws_size,
                              hipStream_t stream) {
    (void)in_sizes; (void)n_in; (void)out_size; (void)ws_size;
    const int*   docs   = (const int*)d_in[0];
    const int*   labels = (const int*)d_in[2];
    const float* embW   = (const float*)d_in[4];
    const float* w_ih   = (const float*)d_in[5];
    const float* w_hh   = (const float*)d_in[6];
    const float* b_ih   = (const float*)d_in[7];
    const float* b_hh   = (const float*)d_in[8];
    const float* cw     = (const float*)d_in[9];
    const float* cb     = (const float*)d_in[10];
    const float* lw     = (const float*)d_in[11];
    const float* lb     = (const float*)d_in[12];
    float* out = (float*)d_out;

    char* ws = (char*)d_ws;
    float*    pre  = (float*)(ws);                    // 8192*1024*4 = 33554432
    float*    hs   = (float*)(ws + 33554432);         // 8192*256*4  =  8388608
    float*    part = (float*)(ws + 41943040);         // 128*128*4   =    65536
    unsigned* hbuf = (unsigned*)(ws + 42008576);      // [2][256] tagged words

    hipMemsetAsync(ws + 42008576, 0, 4096, stream);
    gemm_pre<<<dim3(128, 16, 1), 256, 0, stream>>>(docs, embW, w_ih, b_ih, b_hh, pre);
    lstm_scan<<<NWG, 512, 0, stream>>>(pre, w_hh, hs, hbuf);
    conv_pool<<<128, 256, 0, stream>>>(hs, cw, cb, part);
    final_head<<<1, 128, 0, stream>>>(part, lw, lb, labels, out);
}

// Round 5
// 12463.825 us; speedup vs baseline: 1.5230x; 1.5230x over previous
//
#include <hip/hip_runtime.h>
#include <math.h>

#define T_LEN 8192

typedef float f32x4 __attribute__((ext_vector_type(4)));

// DPP helpers (ctrl must be literal): butterfly within rows of 16 lanes.
#define DPP_ADD(x, ctrl) ((x) + __int_as_float(__builtin_amdgcn_update_dpp(0, __float_as_int(x), (ctrl), 0xF, 0xF, true)))
#define DPP_MAX(x, ctrl) fmaxf((x), __int_as_float(__builtin_amdgcn_update_dpp(0, __float_as_int(x), (ctrl), 0xF, 0xF, true)))

__device__ __forceinline__ float fsig(float x) {
    x = fminf(30.f, fmaxf(-30.f, x));
    float e = __expf(-x);
    return __builtin_amdgcn_rcpf(1.f + e);
}
__device__ __forceinline__ float ftanh(float x) {
    x = fminf(15.f, fmaxf(-15.f, x));
    float e = __expf(-2.f * x);
    return (1.f - e) * __builtin_amdgcn_rcpf(1.f + e);
}

// ---- OCP e4m3fn encode (HW builtin when available, manual RTN fallback) ----
__device__ __forceinline__ unsigned char enc_e4m3(float x) {
#if __has_builtin(__builtin_amdgcn_cvt_pk_fp8_f32)
    int v = __builtin_amdgcn_cvt_pk_fp8_f32(x, 0.f, 0, false);
    return (unsigned char)(v & 0xff);
#else
    unsigned u = __float_as_uint(x);
    unsigned s = (u >> 24) & 0x80u;
    float a = fabsf(x);
    if (a > 448.f) a = 448.f;
    if (a < 9.765625e-4f) return (unsigned char)s;           // < denorm_min/2 -> 0
    int e = ((int)((__float_as_uint(a) >> 23) & 0xffu)) - 127;
    int eu = e < -6 ? -6 : e;
    float ulp = exp2f((float)(eu - 3));
    float q = rintf(a / ulp);
    int mant, ee;
    if (eu == -6 && q < 8.f) { mant = (int)q; ee = 0; }
    else {
        if (q >= 16.f) { q *= 0.5f; eu += 1; }
        mant = (int)q - 8; ee = eu + 7;
        if (ee > 15 || (ee == 15 && mant > 6)) { ee = 15; mant = 6; }
    }
    return (unsigned char)(s | (unsigned)(ee << 3) | (unsigned)mant);
#endif
}
__device__ __forceinline__ unsigned pk4(float a, float b, float c, float d) {
    return (unsigned)enc_e4m3(a) | ((unsigned)enc_e4m3(b) << 8)
         | ((unsigned)enc_e4m3(c) << 16) | ((unsigned)enc_e4m3(d) << 24);
}

// ---------------------------------------------------------------------------
// Kernel 1: pre = relu(embed_W[docs]) @ w_ih^T + (b_ih + b_hh)   (T x 1024)
// Output columns PERMUTED: col' = 4*unit + gate  (unit = j&255, gate = j>>8)
// ---------------------------------------------------------------------------
__global__ __launch_bounds__(256, 4) void gemm_pre(
    const int* __restrict__ docs,
    const float* __restrict__ embW,
    const float* __restrict__ w_ih,
    const float* __restrict__ b_ih,
    const float* __restrict__ b_hh,
    float* __restrict__ pre)
{
    __shared__ __align__(16) float As[16][68];
    __shared__ __align__(16) float Bs[16][68];
    __shared__ int rowid[64];
    const int bt = blockIdx.x;   // 128 t-tiles
    const int bj = blockIdx.y;   // 16 j-tiles
    const int tid = threadIdx.x;
    if (tid < 64) rowid[tid] = docs[bt * 64 + tid];
    __syncthreads();
    const int ti = tid & 15, tj = tid >> 4;
    const int r = tid & 63;
    const int kk4 = (tid >> 6) * 4;
    float acc[4][4];
#pragma unroll
    for (int ii = 0; ii < 4; ++ii)
#pragma unroll
        for (int jj = 0; jj < 4; ++jj) acc[ii][jj] = 0.f;

    for (int k0 = 0; k0 < 256; k0 += 16) {
        float4 av = *(const float4*)(embW + (size_t)rowid[r] * 256 + k0 + kk4);
        float4 bv = *(const float4*)(w_ih + (size_t)(bj * 64 + r) * 256 + k0 + kk4);
        As[kk4 + 0][r] = fmaxf(av.x, 0.f);
        As[kk4 + 1][r] = fmaxf(av.y, 0.f);
        As[kk4 + 2][r] = fmaxf(av.z, 0.f);
        As[kk4 + 3][r] = fmaxf(av.w, 0.f);
        Bs[kk4 + 0][r] = bv.x;
        Bs[kk4 + 1][r] = bv.y;
        Bs[kk4 + 2][r] = bv.z;
        Bs[kk4 + 3][r] = bv.w;
        __syncthreads();
#pragma unroll
        for (int kk = 0; kk < 16; ++kk) {
            float4 a = *(const float4*)&As[kk][ti * 4];
            float4 b = *(const float4*)&Bs[kk][tj * 4];
            acc[0][0] += a.x * b.x; acc[0][1] += a.x * b.y; acc[0][2] += a.x * b.z; acc[0][3] += a.x * b.w;
            acc[1][0] += a.y * b.x; acc[1][1] += a.y * b.y; acc[1][2] += a.y * b.z; acc[1][3] += a.y * b.w;
            acc[2][0] += a.z * b.x; acc[2][1] += a.z * b.y; acc[2][2] += a.z * b.z; acc[2][3] += a.z * b.w;
            acc[3][0] += a.w * b.x; acc[3][1] += a.w * b.y; acc[3][2] += a.w * b.z; acc[3][3] += a.w * b.w;
        }
        __syncthreads();
    }
#pragma unroll
    for (int ii = 0; ii < 4; ++ii) {
        int t = bt * 64 + ti * 4 + ii;
#pragma unroll
        for (int jj = 0; jj < 4; ++jj) {
            int j = bj * 64 + tj * 4 + jj;
            int jp = ((j & 255) << 2) | (j >> 8);   // 4*unit + gate
            pre[(size_t)t * 1024 + jp] = acc[ii][jj] + b_ih[j] + b_hh[j];
        }
    }
}

// ---------------------------------------------------------------------------
// Kernel 2: single-workgroup LSTM scan, fp8 MFMA GEMV.
// 1 WG x 512 threads (8 waves, 2/SIMD, <=256 VGPR). All of W_hh resident in
// VGPRs as e4m3 (x512 scale), rows permuted to 4*unit+gate. Per step:
//   B = fp8(h*64) from LDS (col 0 only; other lanes read a zero page)
//   64 x mfma_f32_16x16x32_fp8_fp8 per wave (8 row-tiles x 8 k-tiles)
//   owner lanes scatter raw gate sums -> per-wave scratch
//   64 lanes: g = acc/32768 + pre ; unified sigmoid (tanh = 2*sig(2x)-1)
//   32 lanes: c,h update; publish h as fp8 to double-buffered LDS; 1 barrier.
// h_{t-1}->h_t handoff is pure LDS: no inter-WG traffic at all.
// ---------------------------------------------------------------------------
__global__ __launch_bounds__(512, 2) void lstm_scan_mfma(
    const float* __restrict__ pre,    // (T, 1024), permuted cols
    const float* __restrict__ w_hh,   // (1024, 256), original layout
    float* __restrict__ hs)           // (T, 256) fp32
{
    const int tid = threadIdx.x;
    const int w  = tid >> 6;          // wave 0..7
    const int l  = tid & 63;
    const int cb = l & 15;            // A-row within tile / C column
    const int kg = l >> 4;            // k-group 0..3
    const bool isown = (cb == 0);
    const float INV = 1.f / 32768.f;

    __shared__ __align__(16) unsigned char h8z[784];   // [0,256)=p0 [256,512)=p1 [512,768)=zeros
    __shared__ __align__(16) float ldsPre[2][1024];
    __shared__ __align__(16) float scr[8][128];

    // ---- load + quantize weights into VGPRs: wf[rowtile][ktile] ----
    long long wf[8][8];
#pragma unroll
    for (int rt = 0; rt < 8; ++rt) {
#pragma unroll
        for (int q = 0; q < 8; ++q) {
            int rowp = ((8 * w + rt) << 4) + cb;         // permuted row = 4u+gate
            int orow = ((rowp & 3) << 8) + (rowp >> 2);  // original gate-major row
            const float* s = w_hh + (size_t)orow * 256 + 32 * q + 8 * kg;
            float4 v0 = *(const float4*)s;
            float4 v1 = *(const float4*)(s + 4);
            unsigned lo = pk4(v0.x * 512.f, v0.y * 512.f, v0.z * 512.f, v0.w * 512.f);
            unsigned hi = pk4(v1.x * 512.f, v1.y * 512.f, v1.z * 512.f, v1.w * 512.f);
            wf[rt][q] = (long long)(((unsigned long long)hi << 32) | (unsigned long long)lo);
        }
    }

    for (int i = tid; i < 784; i += 512) h8z[i] = 0;
    {
        float2 p = *(const float2*)(pre + 2 * tid);       // pre[0] -> ldsPre[0]
        *(float2*)&ldsPre[0][2 * tid] = p;
    }
    float c_st = 0.f, hprev = 0.f;
    const bool isg = ((l & 3) == 2);                      // gate 2 = cell-input (tanh)
    const int ju = 32 * w + l;                            // unit for lanes < 32
    __syncthreads();

    for (int tb = 0; tb < T_LEN; tb += 2) {
#pragma unroll
        for (int sub = 0; sub < 2; ++sub) {
            const int t = tb + sub;
            const int PW = sub;                            // t & 1
            const int PR = sub ^ 1;

            // store h(t-1) (issued early: ancient by the end-of-step barrier)
            if (l < 32) { if (t > 0) hs[(size_t)(t - 1) * 256 + ju] = hprev; }

            // stage next pre row into regs (written to LDS at end of step)
            int tn = (t + 1 < T_LEN) ? t + 1 : T_LEN - 1;
            float2 pv = *(const float2*)(pre + (size_t)tn * 1024 + 2 * tid);

            // B fragments: col-0 lanes read h8, others read the zero page
            unsigned rb = (isown ? (unsigned)(PR * 256) : 512u) + 8u * (unsigned)kg;
            unsigned long long bq[8];
#pragma unroll
            for (int q = 0; q < 8; ++q)
                bq[q] = *(const unsigned long long*)&h8z[rb + 32u * (unsigned)q];

            // MFMA GEMV: acc[rt] accumulates over 8 k-tiles
            f32x4 acc[8];
#pragma unroll
            for (int rt = 0; rt < 8; ++rt) acc[rt] = (f32x4){0.f, 0.f, 0.f, 0.f};
#pragma unroll
            for (int rt = 0; rt < 8; ++rt)
#pragma unroll
                for (int q = 0; q < 8; ++q)
                    acc[rt] = __builtin_amdgcn_mfma_f32_16x16x32_fp8_fp8(
                        (long)wf[rt][q], (long)bq[q], acc[rt], 0, 0, 0);

            // owner lanes scatter raw gate sums to per-wave scratch
            if (isown) {
#pragma unroll
                for (int rt = 0; rt < 8; ++rt)
                    *(f32x4*)&scr[w][16 * rt + 4 * kg] = acc[rt];
            }

            // activations: 64 lanes x 2 values (value v on lane v&63)
            {
                float s0 = scr[w][l],            s1 = scr[w][l + 64];
                float p0 = ldsPre[PW][128 * w + l], p1 = ldsPre[PW][128 * w + l + 64];
                float g0 = fmaf(s0, INV, p0), g1 = fmaf(s1, INV, p1);
                if (isg) { g0 *= 2.f; g1 *= 2.f; }
                float a0 = fsig(g0), a1 = fsig(g1);
                if (isg) { a0 = 2.f * a0 - 1.f; a1 = 2.f * a1 - 1.f; }
                scr[w][l] = a0;
                scr[w][l + 64] = a1;
            }

            // cell update: lanes < 32, one unit each
            if (l < 32) {
                f32x4 g4 = *(const f32x4*)&scr[w][4 * l];
                c_st = g4.y * c_st + g4.x * g4.z;          // c = f*c + i*g
                float h = g4.w * ftanh(c_st);              // h = o*tanh(c)
                hprev = h;
                h8z[PW * 256 + ju] = enc_e4m3(h * 64.f);   // publish fp8 h
            }

            // publish staged pre for step t+1
            *(float2*)&ldsPre[PW ^ 1][2 * tid] = pv;

            __syncthreads();
        }
    }
    if (l < 32) hs[(size_t)(T_LEN - 1) * 256 + ju] = hprev;
}

// ---------------------------------------------------------------------------
// Kernel 3: conv (FN=128, FL=5) over hs + per-block max over its 64 t's.
// ---------------------------------------------------------------------------
__global__ __launch_bounds__(256) void conv_pool(
    const float* __restrict__ hs,    // (T, 256)
    const float* __restrict__ cw,    // (128, 1, 5, 256)
    const float* __restrict__ cb,    // (128,)
    float* __restrict__ part)        // (128 blocks, 128 n)
{
    __shared__ __align__(16) float hst[68 * 260];
    __shared__ __align__(16) float cwS[128 * 68];
    const int blk = blockIdx.x;
    const int t0 = blk * 64;
    const int tid = threadIdx.x;
    const int i = tid & 15;    // t-lane
    const int g = tid >> 4;    // n-group 0..15

    for (int e = tid; e < 68 * 64; e += 256) {
        int rr = e >> 6;
        int c4 = (e & 63) * 4;
        int tg = t0 + rr; if (tg > 8191) tg = 8191;
        float4 v = *(const float4*)(hs + (size_t)tg * 256 + c4);
        *(float4*)&hst[rr * 260 + c4] = v;
    }

    float acc[4][8];
#pragma unroll
    for (int tt = 0; tt < 4; ++tt)
#pragma unroll
        for (int j = 0; j < 8; ++j) acc[tt][j] = 0.f;

    for (int l = 0; l < 5; ++l) {
        for (int hc = 0; hc < 4; ++hc) {
            __syncthreads();
            {
                int n = tid >> 1;
                int hb = (tid & 1) * 32;
                const float* src = cw + (size_t)n * 1280 + l * 256 + hc * 64 + hb;
                float* dst = &cwS[n * 68 + hb];
#pragma unroll
                for (int q = 0; q < 8; ++q) {
                    float4 v = *(const float4*)(src + 4 * q);
                    *(float4*)(dst + 4 * q) = v;
                }
            }
            __syncthreads();
#pragma unroll 4
            for (int q = 0; q < 16; ++q) {
                float4 hvv[4];
#pragma unroll
                for (int tt = 0; tt < 4; ++tt)
                    hvv[tt] = *(const float4*)&hst[(i + 16 * tt + l) * 260 + hc * 64 + 4 * q];
#pragma unroll
                for (int j = 0; j < 8; ++j) {
                    float4 wv = *(const float4*)&cwS[(g + 16 * j) * 68 + 4 * q];
#pragma unroll
                    for (int tt = 0; tt < 4; ++tt) {
                        acc[tt][j] += hvv[tt].x * wv.x + hvv[tt].y * wv.y
                                    + hvv[tt].z * wv.z + hvv[tt].w * wv.w;
                    }
                }
            }
        }
    }

    float m[8];
#pragma unroll
    for (int j = 0; j < 8; ++j) {
        int n = g + 16 * j;
        float cbn = cb[n];
        float mm = -INFINITY;
#pragma unroll
        for (int tt = 0; tt < 4; ++tt) {
            int t = t0 + i + 16 * tt;
            float v = acc[tt][j] + cbn;
            if (t < 8188) mm = fmaxf(mm, v);
        }
        mm = DPP_MAX(mm, 0xB1);
        mm = DPP_MAX(mm, 0x4E);
        mm = DPP_MAX(mm, 0x141);
        mm = DPP_MAX(mm, 0x140);
        m[j] = mm;
    }
    if (i == 0) {
#pragma unroll
        for (int j = 0; j < 8; ++j)
            part[(size_t)blk * 128 + g + 16 * j] = m[j];
    }
}

// ---------------------------------------------------------------------------
// Kernel 4: final head — pool-reduce, logits, log_softmax, loss + acc.
// ---------------------------------------------------------------------------
__global__ void final_head(
    const float* __restrict__ part,      // (128, 128)
    const float* __restrict__ logits_w,  // (20, 128)
    const float* __restrict__ logits_b,  // (20,)
    const int* __restrict__ labels,
    float* __restrict__ out)             // [loss, acc]
{
    __shared__ float pooled[128];
    __shared__ float lgt[20];
    int tid = threadIdx.x;  // 128 threads
    float mx = -INFINITY;
    for (int b = 0; b < 128; ++b) mx = fmaxf(mx, part[(size_t)b * 128 + tid]);
    pooled[tid] = mx;
    __syncthreads();
    if (tid < 20) {
        float s = logits_b[tid];
        for (int k = 0; k < 128; ++k) s += logits_w[tid * 128 + k] * pooled[k];
        lgt[tid] = s;
    }
    __syncthreads();
    if (tid == 0) {
        float m = lgt[0]; int am = 0;
        for (int c2 = 1; c2 < 20; ++c2) { if (lgt[c2] > m) { m = lgt[c2]; am = c2; } }
        float se = 0.f;
        for (int c2 = 0; c2 < 20; ++c2) se += expf(lgt[c2] - m);
        float lse = m + logf(se);
        int lbl = labels[0];
        out[0] = -(lgt[lbl] - lse);
        out[1] = (am == lbl) ? 1.f : 0.f;
    }
}

// ---------------------------------------------------------------------------
extern "C" void kernel_launch(void* const* d_in, const int* in_sizes, int n_in,
                              void* d_out, int out_size, void* d_ws, size_t ws_size,
                              hipStream_t stream) {
    (void)in_sizes; (void)n_in; (void)out_size; (void)ws_size;
    const int*   docs   = (const int*)d_in[0];
    const int*   labels = (const int*)d_in[2];
    const float* embW   = (const float*)d_in[4];
    const float* w_ih   = (const float*)d_in[5];
    const float* w_hh   = (const float*)d_in[6];
    const float* b_ih   = (const float*)d_in[7];
    const float* b_hh   = (const float*)d_in[8];
    const float* cw     = (const float*)d_in[9];
    const float* cb     = (const float*)d_in[10];
    const float* lw     = (const float*)d_in[11];
    const float* lb     = (const float*)d_in[12];
    float* out = (float*)d_out;

    char* ws = (char*)d_ws;
    float* pre  = (float*)(ws);                    // 8192*1024*4 = 33554432
    float* hs   = (float*)(ws + 33554432);         // 8192*256*4  =  8388608
    float* part = (float*)(ws + 41943040);         // 128*128*4   =    65536

    gemm_pre<<<dim3(128, 16, 1), 256, 0, stream>>>(docs, embW, w_ih, b_ih, b_hh, pre);
    lstm_scan_mfma<<<1, 512, 0, stream>>>(pre, w_hh, hs);
    conv_pool<<<128, 256, 0, stream>>>(hs, cw, cb, part);
    final_head<<<1, 128, 0, stream>>>(part, lw, lb, labels, out);
}

// Round 6
// 6991.849 us; speedup vs baseline: 2.7149x; 1.7826x over previous
//
#include <hip/hip_runtime.h>
#include <math.h>

#define T_LEN 8192

typedef float f32x4 __attribute__((ext_vector_type(4)));
typedef int   i32x8 __attribute__((ext_vector_type(8)));

// DPP helpers (ctrl must be literal): butterfly within rows of 16 lanes.
#define DPP_ADD(x, ctrl) ((x) + __int_as_float(__builtin_amdgcn_update_dpp(0, __float_as_int(x), (ctrl), 0xF, 0xF, true)))
#define DPP_MAX(x, ctrl) fmaxf((x), __int_as_float(__builtin_amdgcn_update_dpp(0, __float_as_int(x), (ctrl), 0xF, 0xF, true)))

__device__ __forceinline__ float fsig(float x) {
    x = fminf(30.f, fmaxf(-30.f, x));
    float e = __expf(-x);
    return __builtin_amdgcn_rcpf(1.f + e);
}
__device__ __forceinline__ float ftanh(float x) {
    x = fminf(15.f, fmaxf(-15.f, x));
    float e = __expf(-2.f * x);
    return (1.f - e) * __builtin_amdgcn_rcpf(1.f + e);
}

// ---- OCP e4m3fn encode (HW builtin when available, manual RTN fallback) ----
__device__ __forceinline__ unsigned char enc_e4m3(float x) {
#if __has_builtin(__builtin_amdgcn_cvt_pk_fp8_f32)
    int v = __builtin_amdgcn_cvt_pk_fp8_f32(x, 0.f, 0, false);
    return (unsigned char)(v & 0xff);
#else
    unsigned u = __float_as_uint(x);
    unsigned s = (u >> 24) & 0x80u;
    float a = fabsf(x);
    if (a > 448.f) a = 448.f;
    if (a < 9.765625e-4f) return (unsigned char)s;
    int e = ((int)((__float_as_uint(a) >> 23) & 0xffu)) - 127;
    int eu = e < -6 ? -6 : e;
    float ulp = exp2f((float)(eu - 3));
    float q = rintf(a / ulp);
    int mant, ee;
    if (eu == -6 && q < 8.f) { mant = (int)q; ee = 0; }
    else {
        if (q >= 16.f) { q *= 0.5f; eu += 1; }
        mant = (int)q - 8; ee = eu + 7;
        if (ee > 15 || (ee == 15 && mant > 6)) { ee = 15; mant = 6; }
    }
    return (unsigned char)(s | (unsigned)(ee << 3) | (unsigned)mant);
#endif
}
__device__ __forceinline__ unsigned pk4(float a, float b, float c, float d) {
    return (unsigned)enc_e4m3(a) | ((unsigned)enc_e4m3(b) << 8)
         | ((unsigned)enc_e4m3(c) << 16) | ((unsigned)enc_e4m3(d) << 24);
}

// ---------------------------------------------------------------------------
// Kernel 1: pre = relu(embed_W[docs]) @ w_ih^T + (b_ih + b_hh)   (T x 1024)
// Output columns PERMUTED: col' = 4*unit + gate  (unit = j&255, gate = j>>8)
// ---------------------------------------------------------------------------
__global__ __launch_bounds__(256, 4) void gemm_pre(
    const int* __restrict__ docs,
    const float* __restrict__ embW,
    const float* __restrict__ w_ih,
    const float* __restrict__ b_ih,
    const float* __restrict__ b_hh,
    float* __restrict__ pre)
{
    __shared__ __align__(16) float As[16][68];
    __shared__ __align__(16) float Bs[16][68];
    __shared__ int rowid[64];
    const int bt = blockIdx.x;   // 128 t-tiles
    const int bj = blockIdx.y;   // 16 j-tiles
    const int tid = threadIdx.x;
    if (tid < 64) rowid[tid] = docs[bt * 64 + tid];
    __syncthreads();
    const int ti = tid & 15, tj = tid >> 4;
    const int r = tid & 63;
    const int kk4 = (tid >> 6) * 4;
    float acc[4][4];
#pragma unroll
    for (int ii = 0; ii < 4; ++ii)
#pragma unroll
        for (int jj = 0; jj < 4; ++jj) acc[ii][jj] = 0.f;

    for (int k0 = 0; k0 < 256; k0 += 16) {
        float4 av = *(const float4*)(embW + (size_t)rowid[r] * 256 + k0 + kk4);
        float4 bv = *(const float4*)(w_ih + (size_t)(bj * 64 + r) * 256 + k0 + kk4);
        As[kk4 + 0][r] = fmaxf(av.x, 0.f);
        As[kk4 + 1][r] = fmaxf(av.y, 0.f);
        As[kk4 + 2][r] = fmaxf(av.z, 0.f);
        As[kk4 + 3][r] = fmaxf(av.w, 0.f);
        Bs[kk4 + 0][r] = bv.x;
        Bs[kk4 + 1][r] = bv.y;
        Bs[kk4 + 2][r] = bv.z;
        Bs[kk4 + 3][r] = bv.w;
        __syncthreads();
#pragma unroll
        for (int kk = 0; kk < 16; ++kk) {
            float4 a = *(const float4*)&As[kk][ti * 4];
            float4 b = *(const float4*)&Bs[kk][tj * 4];
            acc[0][0] += a.x * b.x; acc[0][1] += a.x * b.y; acc[0][2] += a.x * b.z; acc[0][3] += a.x * b.w;
            acc[1][0] += a.y * b.x; acc[1][1] += a.y * b.y; acc[1][2] += a.y * b.z; acc[1][3] += a.y * b.w;
            acc[2][0] += a.z * b.x; acc[2][1] += a.z * b.y; acc[2][2] += a.z * b.z; acc[2][3] += a.z * b.w;
            acc[3][0] += a.w * b.x; acc[3][1] += a.w * b.y; acc[3][2] += a.w * b.z; acc[3][3] += a.w * b.w;
        }
        __syncthreads();
    }
#pragma unroll
    for (int ii = 0; ii < 4; ++ii) {
        int t = bt * 64 + ti * 4 + ii;
#pragma unroll
        for (int jj = 0; jj < 4; ++jj) {
            int j = bj * 64 + tj * 4 + jj;
            int jp = ((j & 255) << 2) | (j >> 8);   // 4*unit + gate
            pre[(size_t)t * 1024 + jp] = acc[ii][jj] + b_ih[j] + b_hh[j];
        }
    }
}

// ---------------------------------------------------------------------------
// Kernel 2: single-workgroup LSTM scan, MX-fp8 K=128 MFMA GEMV.
// 1 WG x 512 threads (8 waves, 2/SIMD). W_hh resident in VGPRs as e4m3
// (x512), rows permuted 4*unit+gate. Per step:
//   B = fp8(h*64) broadcast into ALL 16 columns (4x ds_read_b128, broadcast)
//   16 x mfma_scale_f32_16x16x128_f8f6f4 per wave (8 rt x 2 kt), scale=1.0
//   every lane's C frags hold all results (cols identical); col-lane c<8
//   selects tile rt=c via static ladder -> 4 gates in regs -> cell update
//   fully in-register; publish fp8 h byte; ONE barrier per step.
// ---------------------------------------------------------------------------
__global__ __launch_bounds__(512, 2) void lstm_scan_mx(
    const float* __restrict__ pre,    // (T, 1024), permuted cols 4u+gate
    const float* __restrict__ w_hh,   // (1024, 256), original layout
    float* __restrict__ hs)           // (T, 256) fp32
{
    const int tid = threadIdx.x;
    const int w  = tid >> 6;          // wave 0..7
    const int l  = tid & 63;
    const int rw = l & 15;            // A-row within tile / C column
    const int kg = l >> 4;            // k-group 0..3
    const float INV = 1.f / 32768.f;

    __shared__ __align__(16) unsigned char h8[2 * 256];   // fp8 h, dbl-buffered
    __shared__ __align__(16) float ldsPre[2][1024];

    // ---- load + quantize weights: wA[rt][kt], k = 128*kt + 32*kg + j ----
    i32x8 wA[8][2];
#pragma unroll
    for (int rt = 0; rt < 8; ++rt) {
#pragma unroll
        for (int kt = 0; kt < 2; ++kt) {
            int rowp = ((8 * w + rt) << 4) + rw;         // permuted row 4u+gate
            int orow = ((rowp & 3) << 8) + (rowp >> 2);  // original gate-major
            const float* s = w_hh + (size_t)orow * 256 + 128 * kt + 32 * kg;
            i32x8 v;
#pragma unroll
            for (int d = 0; d < 8; ++d) {
                float4 f = *(const float4*)(s + 4 * d);
                v[d] = (int)pk4(f.x * 512.f, f.y * 512.f, f.z * 512.f, f.w * 512.f);
            }
            wA[rt][kt] = v;
        }
    }

    for (int i = tid; i < 512; i += 512) h8[i] = 0;
    {
        float2 p = *(const float2*)(pre + 2 * tid);       // pre[0] -> ldsPre[0]
        *(float2*)&ldsPre[0][2 * tid] = p;
    }
    float c_st = 0.f;
    const bool isup = (rw < 8);
    const int u = 32 * w + 4 * rw + kg;                   // unit (valid if rw<8)
    __syncthreads();

    for (int t = 0; t < T_LEN; ++t) {
        const int PW = t & 1;
        const int PR = PW ^ 1;

        // stage next pre row into regs (LDS write after activations)
        int tn = (t + 1 < T_LEN) ? t + 1 : T_LEN - 1;
        float2 pv = *(const float2*)(pre + (size_t)tn * 1024 + 2 * tid);

        // B: h chunk broadcast to all columns; lane bytes = h[128kt+32kg+j]
        i32x8 bq[2];
#pragma unroll
        for (int kt = 0; kt < 2; ++kt) {
            const unsigned char* bp = &h8[PR * 256 + 128 * kt + 32 * kg];
            uint4 lo = *(const uint4*)bp;
            uint4 hi = *(const uint4*)(bp + 16);
            i32x8 b;
            b[0] = (int)lo.x; b[1] = (int)lo.y; b[2] = (int)lo.z; b[3] = (int)lo.w;
            b[4] = (int)hi.x; b[5] = (int)hi.y; b[6] = (int)hi.z; b[7] = (int)hi.w;
            bq[kt] = b;
        }

        // MFMA GEMV: 8 row-tiles x 2 k-tiles, fmt fp8/fp8, scales = 1.0
        f32x4 acc[8];
#pragma unroll
        for (int rt = 0; rt < 8; ++rt) acc[rt] = (f32x4){0.f, 0.f, 0.f, 0.f};
#pragma unroll
        for (int rt = 0; rt < 8; ++rt)
#pragma unroll
            for (int kt = 0; kt < 2; ++kt)
                acc[rt] = __builtin_amdgcn_mfma_scale_f32_16x16x128_f8f6f4(
                    wA[rt][kt], bq[kt], acc[rt],
                    0, 0,                      // cbsz: A fmt fp8, blgp: B fmt fp8
                    0, 0x7f7f7f7f,             // scale A: opsel, e8m0 1.0
                    0, 0x7f7f7f7f);            // scale B: opsel, e8m0 1.0

        // cell update: col-lane rw<8 handles tile rt=rw (static ladder select)
        if (isup) {
            f32x4 av = acc[0];
            av = (rw == 1) ? acc[1] : av;
            av = (rw == 2) ? acc[2] : av;
            av = (rw == 3) ? acc[3] : av;
            av = (rw == 4) ? acc[4] : av;
            av = (rw == 5) ? acc[5] : av;
            av = (rw == 6) ? acc[6] : av;
            av = (rw == 7) ? acc[7] : av;
            f32x4 p4 = *(const f32x4*)&ldsPre[PW][4 * u];
            float gi = fmaf(av.x, INV, p4.x);
            float gf = fmaf(av.y, INV, p4.y);
            float gg = fmaf(av.z, INV, p4.z);
            float go = fmaf(av.w, INV, p4.w);
            float si = fsig(gi);
            float sf = fsig(gf);
            float tg = ftanh(gg);
            float so = fsig(go);
            c_st = sf * c_st + si * tg;
            float h = so * ftanh(c_st);
            hs[(size_t)t * 256 + u] = h;
            h8[PW * 256 + u] = enc_e4m3(h * 64.f);
        }

        // publish staged pre for step t+1
        *(float2*)&ldsPre[PR][2 * tid] = pv;

        __syncthreads();
    }
}

// ---------------------------------------------------------------------------
// Kernel 3: conv (FN=128, FL=5) over hs + per-block max over its 64 t's.
// ---------------------------------------------------------------------------
__global__ __launch_bounds__(256) void conv_pool(
    const float* __restrict__ hs,    // (T, 256)
    const float* __restrict__ cw,    // (128, 1, 5, 256)
    const float* __restrict__ cb,    // (128,)
    float* __restrict__ part)        // (128 blocks, 128 n)
{
    __shared__ __align__(16) float hst[68 * 260];
    __shared__ __align__(16) float cwS[128 * 68];
    const int blk = blockIdx.x;
    const int t0 = blk * 64;
    const int tid = threadIdx.x;
    const int i = tid & 15;    // t-lane
    const int g = tid >> 4;    // n-group 0..15

    for (int e = tid; e < 68 * 64; e += 256) {
        int rr = e >> 6;
        int c4 = (e & 63) * 4;
        int tg = t0 + rr; if (tg > 8191) tg = 8191;
        float4 v = *(const float4*)(hs + (size_t)tg * 256 + c4);
        *(float4*)&hst[rr * 260 + c4] = v;
    }

    float acc[4][8];
#pragma unroll
    for (int tt = 0; tt < 4; ++tt)
#pragma unroll
        for (int j = 0; j < 8; ++j) acc[tt][j] = 0.f;

    for (int l = 0; l < 5; ++l) {
        for (int hc = 0; hc < 4; ++hc) {
            __syncthreads();
            {
                int n = tid >> 1;
                int hb = (tid & 1) * 32;
                const float* src = cw + (size_t)n * 1280 + l * 256 + hc * 64 + hb;
                float* dst = &cwS[n * 68 + hb];
#pragma unroll
                for (int q = 0; q < 8; ++q) {
                    float4 v = *(const float4*)(src + 4 * q);
                    *(float4*)(dst + 4 * q) = v;
                }
            }
            __syncthreads();
#pragma unroll 4
            for (int q = 0; q < 16; ++q) {
                float4 hvv[4];
#pragma unroll
                for (int tt = 0; tt < 4; ++tt)
                    hvv[tt] = *(const float4*)&hst[(i + 16 * tt + l) * 260 + hc * 64 + 4 * q];
#pragma unroll
                for (int j = 0; j < 8; ++j) {
                    float4 wv = *(const float4*)&cwS[(g + 16 * j) * 68 + 4 * q];
#pragma unroll
                    for (int tt = 0; tt < 4; ++tt) {
                        acc[tt][j] += hvv[tt].x * wv.x + hvv[tt].y * wv.y
                                    + hvv[tt].z * wv.z + hvv[tt].w * wv.w;
                    }
                }
            }
        }
    }

    float m[8];
#pragma unroll
    for (int j = 0; j < 8; ++j) {
        int n = g + 16 * j;
        float cbn = cb[n];
        float mm = -INFINITY;
#pragma unroll
        for (int tt = 0; tt < 4; ++tt) {
            int t = t0 + i + 16 * tt;
            float v = acc[tt][j] + cbn;
            if (t < 8188) mm = fmaxf(mm, v);
        }
        mm = DPP_MAX(mm, 0xB1);
        mm = DPP_MAX(mm, 0x4E);
        mm = DPP_MAX(mm, 0x141);
        mm = DPP_MAX(mm, 0x140);
        m[j] = mm;
    }
    if (i == 0) {
#pragma unroll
        for (int j = 0; j < 8; ++j)
            part[(size_t)blk * 128 + g + 16 * j] = m[j];
    }
}

// ---------------------------------------------------------------------------
// Kernel 4: final head — pool-reduce, logits, log_softmax, loss + acc.
// ---------------------------------------------------------------------------
__global__ void final_head(
    const float* __restrict__ part,      // (128, 128)
    const float* __restrict__ logits_w,  // (20, 128)
    const float* __restrict__ logits_b,  // (20,)
    const int* __restrict__ labels,
    float* __restrict__ out)             // [loss, acc]
{
    __shared__ float pooled[128];
    __shared__ float lgt[20];
    int tid = threadIdx.x;  // 128 threads
    float mx = -INFINITY;
    for (int b = 0; b < 128; ++b) mx = fmaxf(mx, part[(size_t)b * 128 + tid]);
    pooled[tid] = mx;
    __syncthreads();
    if (tid < 20) {
        float s = logits_b[tid];
        for (int k = 0; k < 128; ++k) s += logits_w[tid * 128 + k] * pooled[k];
        lgt[tid] = s;
    }
    __syncthreads();
    if (tid == 0) {
        float m = lgt[0]; int am = 0;
        for (int c2 = 1; c2 < 20; ++c2) { if (lgt[c2] > m) { m = lgt[c2]; am = c2; } }
        float se = 0.f;
        for (int c2 = 0; c2 < 20; ++c2) se += expf(lgt[c2] - m);
        float lse = m + logf(se);
        int lbl = labels[0];
        out[0] = -(lgt[lbl] - lse);
        out[1] = (am == lbl) ? 1.f : 0.f;
    }
}

// ---------------------------------------------------------------------------
extern "C" void kernel_launch(void* const* d_in, const int* in_sizes, int n_in,
                              void* d_out, int out_size, void* d_ws, size_t ws_size,
                              hipStream_t stream) {
    (void)in_sizes; (void)n_in; (void)out_size; (void)ws_size;
    const int*   docs   = (const int*)d_in[0];
    const int*   labels = (const int*)d_in[2];
    const float* embW   = (const float*)d_in[4];
    const float* w_ih   = (const float*)d_in[5];
    const float* w_hh   = (const float*)d_in[6];
    const float* b_ih   = (const float*)d_in[7];
    const float* b_hh   = (const float*)d_in[8];
    const float* cw     = (const float*)d_in[9];
    const float* cb     = (const float*)d_in[10];
    const float* lw     = (const float*)d_in[11];
    const float* lb     = (const float*)d_in[12];
    float* out = (float*)d_out;

    char* ws = (char*)d_ws;
    float* pre  = (float*)(ws);                    // 8192*1024*4 = 33554432
    float* hs   = (float*)(ws + 33554432);         // 8192*256*4  =  8388608
    float* part = (float*)(ws + 41943040);         // 128*128*4   =    65536

    gemm_pre<<<dim3(128, 16, 1), 256, 0, stream>>>(docs, embW, w_ih, b_ih, b_hh, pre);
    lstm_scan_mx<<<1, 512, 0, stream>>>(pre, w_hh, hs);
    conv_pool<<<128, 256, 0, stream>>>(hs, cw, cb, part);
    final_head<<<1, 128, 0, stream>>>(part, lw, lb, labels, out);
}